// Round 10
// baseline (151.378 us; speedup 1.0000x reference)
//
#include <hip/hip_runtime.h>

#define NN 256
#define EHID 14
#define NTICK (32 * 256)

typedef short short8 __attribute__((ext_vector_type(8)));
typedef float f32x16 __attribute__((ext_vector_type(16)));

__device__ __forceinline__ float sigm(float x) {
    return __builtin_amdgcn_rcpf(1.0f + __expf(-x));
}
__device__ __forceinline__ unsigned int bfbits(float f) {
    unsigned int u = __builtin_bit_cast(unsigned int, f);
    return (u + 0x7FFFu + ((u >> 16) & 1u)) >> 16;
}
__device__ __forceinline__ unsigned int cvtpk(float lo, float hi) {
    unsigned int r;
    asm("v_cvt_pk_bf16_f32 %0, %1, %2" : "=v"(r) : "v"(lo), "v"(hi));
    return r;
}
__device__ __forceinline__ short8 mk8(unsigned a, unsigned b, unsigned c, unsigned d) {
    int4 t = make_int4((int)a, (int)b, (int)c, (int)d);
    return __builtin_bit_cast(short8, t);
}

// Persistent waves + atomic ticket queue. 4096 waves stay resident for the
// whole kernel (no workgroup churn — R4-R9 showed occupancy never exceeded
// ~17% with retire/refill churn). Weight fragments hoisted once per wave
// (R9 lesson: replicating prologue/epilogue 4x per i cost +60% busy cycles).
// No min-waves launch_bounds (R3 spill), no 8-deep unroll (R5 VGPR blowup),
// no sched_barrier (R8 serialized its own ILP).
__global__ __launch_bounds__(512) void egnn_persist(
    const float* __restrict__ x,
    const float* __restrict__ W1, const float* __restrict__ b1,
    const float* __restrict__ W2, const float* __restrict__ b2,
    const float* __restrict__ Wg, const float* __restrict__ bg,
    const float* __restrict__ gamma, const float* __restrict__ beta,
    const float* __restrict__ Wn1, const float* __restrict__ bn1,
    const float* __restrict__ Wn2, const float* __restrict__ bn2,
    const int* __restrict__ mask, float* __restrict__ out,
    int* __restrict__ tick)
{
    const int l    = threadIdx.x & 63;
    const int l31  = l & 31;
    const int half = l >> 5;

    // ---- wave-invariant weight fragments (once per persistent wave) ----
    unsigned a1p[4];
#pragma unroll
    for (int e2 = 0; e2 < 4; ++e2) {
        const int k0 = 8*half + 2*e2, k1 = k0 + 1;
        float w0 = 0.f, w1 = 0.f;
        if (l31 < EHID) {
            w0 = (k0 < 7) ? W1[k0*EHID + l31] : ((k0 == 7) ? b1[l31] : 0.f);
            w1 = (k1 < 7) ? W1[k1*EHID + l31] : ((k1 == 7) ? b1[l31] : 0.f);
        }
        a1p[e2] = bfbits(w0) | (bfbits(w1) << 16);
    }
    const short8 A1 = mk8(a1p[0], a1p[1], a1p[2], a1p[3]);

    unsigned a2p[2][4];
#pragma unroll
    for (int mf = 0; mf < 2; ++mf) {
        const int ch = l31 + 32*mf;
#pragma unroll
        for (int e2 = 0; e2 < 4; ++e2) {
            const int k0 = 8*half + 2*e2, k1 = k0 + 1;
            const float w0 = (k0 < EHID) ? W2[k0*64 + ch] : ((k0 == EHID) ? b2[ch] : 0.f);
            const float w1 = (k1 < EHID) ? W2[k1*64 + ch] : ((k1 == EHID) ? b2[ch] : 0.f);
            a2p[mf][e2] = bfbits(w0) | (bfbits(w1) << 16);
        }
    }
    const short8 A20 = mk8(a2p[0][0], a2p[0][1], a2p[0][2], a2p[0][3]);
    const short8 A21 = mk8(a2p[1][0], a2p[1][1], a2p[1][2], a2p[1][3]);

    float wgv0[16], wgv1[16];
#pragma unroll
    for (int r = 0; r < 16; ++r) {
        const int row = (r & 3) + 8*(r >> 2) + 4*half;
        wgv0[r] = Wg[row];
        wgv1[r] = Wg[row + 32];
    }
    const float bg0 = bg[0];

    f32x16 zc;
#pragma unroll
    for (int r = 0; r < 16; ++r) zc[r] = 0.f;

    // ---- ticket loop ----
    for (;;) {
        int t0 = 0;
        if (l == 0) t0 = atomicAdd(tick, 1);
        const int t = __shfl(t0, 0, 64);
        if (t >= NTICK) break;

        const int b = t >> 8;
        const int i = t & 255;
        const int gi = t;
        const float* xb   = x + b * (NN * 3);
        const int*   mrow = mask + b * NN;
        const float xi0 = xb[i*3+0], xi1 = xb[i*3+1], xi2 = xb[i*3+2];
        const int   mi  = mrow[i];

        float pn[6];
#pragma unroll
        for (int u = 0; u < 6; ++u) pn[u] = 0.f;

        if (mi) {
            unsigned long long mb[4];
#pragma unroll
            for (int tt = 0; tt < 4; ++tt)
                mb[tt] = __ballot(mrow[tt*64 + l] != 0);

            float macc0[16], macc1[16];
#pragma unroll
            for (int r = 0; r < 16; ++r) { macc0[r] = 0.f; macc1[r] = 0.f; }

            const unsigned p0 = cvtpk(xi0, xi1);   // k0,k1 constant over rounds

#pragma unroll 2
            for (int rnd = 0; rnd < 8; ++rnd) {
                const int e = rnd*32 + l31;
                const float xj0 = xb[e*3+0], xj1 = xb[e*3+1], xj2 = xb[e*3+2];
                const float r0 = xi0-xj0, r1 = xi1-xj1, r2 = xi2-xj2;
                const float rd = r0*r0 + r1*r1 + r2*r2;
                const short8 B1 = mk8(p0, cvtpk(xi2, xj0), cvtpk(xj1, xj2),
                                      cvtpk(rd, 1.0f));   // k6=rel_dist, k7=bias

                const f32x16 c = __builtin_amdgcn_mfma_f32_32x32x16_bf16(A1, B1, zc, 0, 0, 0);

                float s[8];
#pragma unroll
                for (int r = 0; r < 8; ++r) s[r] = c[r] * sigm(c[r]);
                const unsigned q01 = cvtpk(s[0], s[1]);
                const unsigned q23 = cvtpk(s[2], s[3]);
                const unsigned q45 = cvtpk(s[4], s[5]);
                const unsigned q67 = cvtpk(s[6], s[7]);
                const unsigned sendA = half ? q01 : q45;
                const unsigned sendB = half ? q23 : q67;
                const unsigned recvA = (unsigned)__shfl_xor((int)sendA, 32, 64);
                const unsigned recvB = (unsigned)__shfl_xor((int)sendB, 32, 64);
                const unsigned w0 = half ? recvA : q01;          // k(0,1)  | k(8,9)
                const unsigned w1 = half ? recvB : q23;          // k(2,3)  | k(10,11)
                const unsigned w2 = half ? q45   : recvA;        // k(4,5)  | k(12,13)
                const unsigned w3 = half ? 0x00003F80u : recvB;  // k(6,7)  | k14=1(b2),k15=0
                const short8 B2 = mk8(w0, w1, w2, w3);

                const f32x16 c0 = __builtin_amdgcn_mfma_f32_32x32x16_bf16(A20, B2, zc, 0, 0, 0);
                const f32x16 c1 = __builtin_amdgcn_mfma_f32_32x32x16_bf16(A21, B2, zc, 0, 0, 0);

                float v0[16], v1[16];
                float gpa = 0.f, gpb = 0.f, gpc = 0.f, gpd = 0.f;
#pragma unroll
                for (int r = 0; r < 16; ++r) {
                    v0[r] = c0[r] * sigm(c0[r]);
                    v1[r] = c1[r] * sigm(c1[r]);
                    if (r < 8) { gpa += v0[r] * wgv0[r]; gpc += v1[r] * wgv1[r]; }
                    else       { gpb += v0[r] * wgv0[r]; gpd += v1[r] * wgv1[r]; }
                }
                const float gp = (gpa + gpb) + (gpc + gpd);
                const float go = __shfl_xor(gp, 32, 64);
                float g = sigm(gp + go + bg0);
                const unsigned mhw = (unsigned)(mb[rnd >> 1] >> ((rnd & 1) * 32));
                g = ((mhw >> l31) & 1u) ? g : 0.f;
#pragma unroll
                for (int r = 0; r < 16; ++r) {
                    macc0[r] += v0[r] * g;
                    macc1[r] += v1[r] * g;
                }
            }

            // project through Wn1 (commutes with edge-sum), butterfly-reduce
#pragma unroll
            for (int r = 0; r < 16; ++r) {
                const int row = (r & 3) + 8*(r >> 2) + 4*half;
                const float m0 = macc0[r], m1 = macc1[r];
                const float* wr0 = Wn1 + (3 + row) * 6;
                const float* wr1 = Wn1 + (3 + row + 32) * 6;
#pragma unroll
                for (int u = 0; u < 6; ++u) pn[u] += m0 * wr0[u] + m1 * wr1[u];
            }
#pragma unroll
            for (int sft = 1; sft <= 32; sft <<= 1) {
#pragma unroll
                for (int u = 0; u < 6; ++u) pn[u] += __shfl_xor(pn[u], sft, 64);
            }
        }

        // ---- node finish ----
        const float mu  = (xi0 + xi1 + xi2) * (1.f/3.f);
        const float d0  = xi0 - mu, d1 = xi1 - mu, d2 = xi2 - mu;
        const float var = (d0*d0 + d1*d1 + d2*d2) * (1.f/3.f);
        const float rs  = rsqrtf(var + 1e-5f);
        const float n0  = d0*rs*gamma[0] + beta[0];
        const float n1  = d1*rs*gamma[1] + beta[1];
        const float n2  = d2*rs*gamma[2] + beta[2];
        float ss[6];
#pragma unroll
        for (int u = 0; u < 6; ++u) {
            const float sv = pn[u] + bn1[u] + n0*Wn1[u] + n1*Wn1[6+u] + n2*Wn1[12+u];
            ss[u] = sv * sigm(sv);
        }
        if (l < 3) {
            const float xres = (l == 0) ? xi0 : ((l == 1) ? xi1 : xi2);
            float sv = bn2[l] + xres;
#pragma unroll
            for (int u = 0; u < 6; ++u) sv += ss[u] * Wn2[u*3 + l];
            out[gi*3 + l] = sv;
        }
    }
}

extern "C" void kernel_launch(void* const* d_in, const int* in_sizes, int n_in,
                              void* d_out, int out_size, void* d_ws, size_t ws_size,
                              hipStream_t stream) {
    (void)in_sizes; (void)n_in; (void)out_size; (void)ws_size;
    const float* x     = (const float*)d_in[0];
    const float* W1    = (const float*)d_in[1];
    const float* b1    = (const float*)d_in[2];
    const float* W2    = (const float*)d_in[3];
    const float* b2    = (const float*)d_in[4];
    const float* Wg    = (const float*)d_in[5];
    const float* bg    = (const float*)d_in[6];
    const float* gamma = (const float*)d_in[7];
    const float* beta  = (const float*)d_in[8];
    const float* Wn1   = (const float*)d_in[9];
    const float* bn1   = (const float*)d_in[10];
    const float* Wn2   = (const float*)d_in[11];
    const float* bn2   = (const float*)d_in[12];
    const int*   mask  = (const int*)d_in[13];
    float* out = (float*)d_out;
    int*   tick = (int*)d_ws;

    hipMemsetAsync(tick, 0, sizeof(int), stream);
    // 512 blocks x 8 waves = 4096 persistent waves (~4/SIMD), resident
    // start-to-finish; ticket queue load-balances masked i's.
    hipLaunchKernelGGL(egnn_persist, dim3(512), dim3(512), 0, stream,
                       x, W1, b1, W2, b2, Wg, bg, gamma, beta,
                       Wn1, bn1, Wn2, bn2, mask, out, tick);
}

// Round 11
// 50.076 us; speedup vs baseline: 3.0230x; 3.0230x over previous
//
#include <hip/hip_runtime.h>

#define NN 256
#define EHID 14

typedef short short8 __attribute__((ext_vector_type(8)));
typedef float f32x16 __attribute__((ext_vector_type(16)));

__device__ __forceinline__ float sigm(float x) {
    return __builtin_amdgcn_rcpf(1.0f + __expf(-x));
}
__device__ __forceinline__ unsigned int bfbits(float f) {
    unsigned int u = __builtin_bit_cast(unsigned int, f);
    return (u + 0x7FFFu + ((u >> 16) & 1u)) >> 16;
}
__device__ __forceinline__ unsigned int cvtpk(float lo, float hi) {
    unsigned int r;
    asm("v_cvt_pk_bf16_f32 %0, %1, %2" : "=v"(r) : "v"(lo), "v"(hi));
    return r;
}
__device__ __forceinline__ short8 mk8(unsigned a, unsigned b, unsigned c, unsigned d) {
    int4 t = make_int4((int)a, (int)b, (int)c, (int)d);
    return __builtin_bit_cast(short8, t);
}

// ---- Kernel A: compact masked-j coordinates per batch (SoA), j-ascending ----
// No atomics (R10: 8K same-address atomics cost ~100us), no memset needed
// (xc/jcnt fully rewritten every launch -> deterministic).
__global__ __launch_bounds__(256) void egnn_prep(
    const float* __restrict__ x, const int* __restrict__ mask,
    float* __restrict__ xc0, float* __restrict__ xc1,
    float* __restrict__ xc2, int* __restrict__ jcnt)
{
    __shared__ unsigned long long wbal[4];
    const int b   = blockIdx.x;
    const int tid = threadIdx.x;
    const int w   = tid >> 6;
    const int l   = tid & 63;
    const int gi  = b * NN + tid;
    const int m   = mask[gi];

    const unsigned long long ball = __ballot(m != 0);
    if (l == 0) wbal[w] = ball;
    __syncthreads();

    int jbase = 0;
#pragma unroll
    for (int t = 0; t < 4; ++t) if (t < w) jbase += __popcll(wbal[t]);
    const int prefix = __popcll(ball & ((1ull << l) - 1ull));

    if (m) {
        const int idx = b * NN + jbase + prefix;   // j-ascending => deterministic sums
        xc0[idx] = x[gi*3+0];
        xc1[idx] = x[gi*3+1];
        xc2[idx] = x[gi*3+2];
    }
    if (tid == 0) {
        int s = 0;
#pragma unroll
        for (int t = 0; t < 4; ++t) s += __popcll(wbal[t]);
        jcnt[b] = s;
    }
}

// ---- Kernel B: R4 structure (one i per wave, 8192 waves) but rounds over
// COMPACTED coords: ceil(jcnt/32) ~ 4 avg instead of 8; no per-round mask
// logic; sequential coalesced SoA loads (R7's jlist->x gather chain removed).
// No min-waves launch_bounds (R3 spill); no full unroll (R5 VGPR blowup);
// no sched_barrier (R8); no ticket atomics (R10).
__global__ __launch_bounds__(256) void egnn_edges(
    const float* __restrict__ x,
    const float* __restrict__ W1, const float* __restrict__ b1,
    const float* __restrict__ W2, const float* __restrict__ b2,
    const float* __restrict__ Wg, const float* __restrict__ bg,
    const float* __restrict__ gamma, const float* __restrict__ beta,
    const float* __restrict__ Wn1, const float* __restrict__ bn1,
    const float* __restrict__ Wn2, const float* __restrict__ bn2,
    const int* __restrict__ mask, float* __restrict__ out,
    const float* __restrict__ xc0, const float* __restrict__ xc1,
    const float* __restrict__ xc2, const int* __restrict__ jcnt)
{
    const int tid  = threadIdx.x;
    const int wid  = tid >> 6;
    const int l    = tid & 63;
    const int l31  = l & 31;
    const int half = l >> 5;
    const int gi   = blockIdx.x * 4 + wid;   // one (b,i) per wave
    const int b    = gi >> 8;
    const int i    = gi & 255;

    const float* xb = x + b * (NN * 3);
    const float xi0 = xb[i*3+0], xi1 = xb[i*3+1], xi2 = xb[i*3+2];
    const int   mi  = mask[gi];

    float pn[6];
#pragma unroll
    for (int u = 0; u < 6; ++u) pn[u] = 0.f;

    if (mi) {
        // ---- wave-invariant weight fragments ----
        unsigned a1p[4];
#pragma unroll
        for (int e2 = 0; e2 < 4; ++e2) {
            const int k0 = 8*half + 2*e2, k1 = k0 + 1;
            float w0 = 0.f, w1 = 0.f;
            if (l31 < EHID) {
                w0 = (k0 < 7) ? W1[k0*EHID + l31] : ((k0 == 7) ? b1[l31] : 0.f);
                w1 = (k1 < 7) ? W1[k1*EHID + l31] : ((k1 == 7) ? b1[l31] : 0.f);
            }
            a1p[e2] = bfbits(w0) | (bfbits(w1) << 16);
        }
        const short8 A1 = mk8(a1p[0], a1p[1], a1p[2], a1p[3]);

        unsigned a2p[2][4];
#pragma unroll
        for (int mf = 0; mf < 2; ++mf) {
            const int ch = l31 + 32*mf;
#pragma unroll
            for (int e2 = 0; e2 < 4; ++e2) {
                const int k0 = 8*half + 2*e2, k1 = k0 + 1;
                const float w0 = (k0 < EHID) ? W2[k0*64 + ch] : ((k0 == EHID) ? b2[ch] : 0.f);
                const float w1 = (k1 < EHID) ? W2[k1*64 + ch] : ((k1 == EHID) ? b2[ch] : 0.f);
                a2p[mf][e2] = bfbits(w0) | (bfbits(w1) << 16);
            }
        }
        const short8 A20 = mk8(a2p[0][0], a2p[0][1], a2p[0][2], a2p[0][3]);
        const short8 A21 = mk8(a2p[1][0], a2p[1][1], a2p[1][2], a2p[1][3]);

        float wgv0[16], wgv1[16];
#pragma unroll
        for (int r = 0; r < 16; ++r) {
            const int row = (r & 3) + 8*(r >> 2) + 4*half;
            wgv0[r] = Wg[row];
            wgv1[r] = Wg[row + 32];
        }
        const float bg0 = bg[0];

        const int jc = jcnt[b];
        const int rounds = (jc + 31) >> 5;
        const float* c0p = xc0 + b * NN;
        const float* c1p = xc1 + b * NN;
        const float* c2p = xc2 + b * NN;

        float macc0[16], macc1[16];
#pragma unroll
        for (int r = 0; r < 16; ++r) { macc0[r] = 0.f; macc1[r] = 0.f; }

        f32x16 zc;
#pragma unroll
        for (int r = 0; r < 16; ++r) zc[r] = 0.f;

        const unsigned p0 = cvtpk(xi0, xi1);   // k0,k1 constant over rounds

#pragma unroll 2
        for (int rnd = 0; rnd < rounds; ++rnd) {
            const int e     = rnd*32 + l31;
            const int valid = e < jc;
            const int ei    = valid ? e : 0;   // dup j0 on tail; killed by g=0
            const float xj0 = c0p[ei], xj1 = c1p[ei], xj2 = c2p[ei];

            const float r0 = xi0-xj0, r1 = xi1-xj1, r2 = xi2-xj2;
            const float rd = r0*r0 + r1*r1 + r2*r2;
            const short8 B1 = mk8(p0, cvtpk(xi2, xj0), cvtpk(xj1, xj2),
                                  cvtpk(rd, 1.0f));   // k6=rel_dist, k7=bias

            const f32x16 c = __builtin_amdgcn_mfma_f32_32x32x16_bf16(A1, B1, zc, 0, 0, 0);

            float s[8];
#pragma unroll
            for (int r = 0; r < 8; ++r) s[r] = c[r] * sigm(c[r]);
            const unsigned q01 = cvtpk(s[0], s[1]);
            const unsigned q23 = cvtpk(s[2], s[3]);
            const unsigned q45 = cvtpk(s[4], s[5]);
            const unsigned q67 = cvtpk(s[6], s[7]);
            const unsigned sendA = half ? q01 : q45;
            const unsigned sendB = half ? q23 : q67;
            const unsigned recvA = (unsigned)__shfl_xor((int)sendA, 32, 64);
            const unsigned recvB = (unsigned)__shfl_xor((int)sendB, 32, 64);
            const unsigned w0 = half ? recvA : q01;          // k(0,1)  | k(8,9)
            const unsigned w1 = half ? recvB : q23;          // k(2,3)  | k(10,11)
            const unsigned w2 = half ? q45   : recvA;        // k(4,5)  | k(12,13)
            const unsigned w3 = half ? 0x00003F80u : recvB;  // k(6,7)  | k14=1(b2),k15=0
            const short8 B2 = mk8(w0, w1, w2, w3);

            const f32x16 c0 = __builtin_amdgcn_mfma_f32_32x32x16_bf16(A20, B2, zc, 0, 0, 0);
            const f32x16 c1 = __builtin_amdgcn_mfma_f32_32x32x16_bf16(A21, B2, zc, 0, 0, 0);

            float v0[16], v1[16];
            float gpa = 0.f, gpb = 0.f, gpc = 0.f, gpd = 0.f;  // 4 gate chains
#pragma unroll
            for (int r = 0; r < 16; ++r) {
                v0[r] = c0[r] * sigm(c0[r]);
                v1[r] = c1[r] * sigm(c1[r]);
                if (r < 8) { gpa += v0[r] * wgv0[r]; gpc += v1[r] * wgv1[r]; }
                else       { gpb += v0[r] * wgv0[r]; gpd += v1[r] * wgv1[r]; }
            }
            const float gp = (gpa + gpb) + (gpc + gpd);
            const float go = __shfl_xor(gp, 32, 64);
            float g = sigm(gp + go + bg0);
            g = valid ? g : 0.f;
#pragma unroll
            for (int r = 0; r < 16; ++r) {
                macc0[r] += v0[r] * g;
                macc1[r] += v1[r] * g;
            }
        }

        // project through Wn1 (linear; commutes with edge-sum), butterfly
#pragma unroll
        for (int r = 0; r < 16; ++r) {
            const int row = (r & 3) + 8*(r >> 2) + 4*half;
            const float m0 = macc0[r], m1 = macc1[r];
            const float* wr0 = Wn1 + (3 + row) * 6;
            const float* wr1 = Wn1 + (3 + row + 32) * 6;
#pragma unroll
            for (int u = 0; u < 6; ++u) pn[u] += m0 * wr0[u] + m1 * wr1[u];
        }
#pragma unroll
        for (int sft = 1; sft <= 32; sft <<= 1) {
#pragma unroll
            for (int u = 0; u < 6; ++u) pn[u] += __shfl_xor(pn[u], sft, 64);
        }
    }

    // ---- node finish (all i) ----
    const float mu  = (xi0 + xi1 + xi2) * (1.f/3.f);
    const float d0  = xi0 - mu, d1 = xi1 - mu, d2 = xi2 - mu;
    const float var = (d0*d0 + d1*d1 + d2*d2) * (1.f/3.f);
    const float rs  = rsqrtf(var + 1e-5f);
    const float n0  = d0*rs*gamma[0] + beta[0];
    const float n1  = d1*rs*gamma[1] + beta[1];
    const float n2  = d2*rs*gamma[2] + beta[2];
    float ss[6];
#pragma unroll
    for (int u = 0; u < 6; ++u) {
        const float sv = pn[u] + bn1[u] + n0*Wn1[u] + n1*Wn1[6+u] + n2*Wn1[12+u];
        ss[u] = sv * sigm(sv);
    }
    if (l < 3) {
        const float xres = (l == 0) ? xi0 : ((l == 1) ? xi1 : xi2);
        float sv = bn2[l] + xres;
#pragma unroll
        for (int u = 0; u < 6; ++u) sv += ss[u] * Wn2[u*3 + l];
        out[gi*3 + l] = sv;
    }
}

extern "C" void kernel_launch(void* const* d_in, const int* in_sizes, int n_in,
                              void* d_out, int out_size, void* d_ws, size_t ws_size,
                              hipStream_t stream) {
    (void)in_sizes; (void)n_in; (void)out_size; (void)ws_size;
    const float* x     = (const float*)d_in[0];
    const float* W1    = (const float*)d_in[1];
    const float* b1    = (const float*)d_in[2];
    const float* W2    = (const float*)d_in[3];
    const float* b2    = (const float*)d_in[4];
    const float* Wg    = (const float*)d_in[5];
    const float* bg    = (const float*)d_in[6];
    const float* gamma = (const float*)d_in[7];
    const float* beta  = (const float*)d_in[8];
    const float* Wn1   = (const float*)d_in[9];
    const float* bn1   = (const float*)d_in[10];
    const float* Wn2   = (const float*)d_in[11];
    const float* bn2   = (const float*)d_in[12];
    const int*   mask  = (const int*)d_in[13];
    float* out = (float*)d_out;

    float* xc0 = (float*)d_ws;                              // 32KB
    float* xc1 = (float*)((char*)d_ws + 32*1024);           // 32KB
    float* xc2 = (float*)((char*)d_ws + 64*1024);           // 32KB
    int*   jcn = (int*)  ((char*)d_ws + 96*1024);           // 128B

    hipLaunchKernelGGL(egnn_prep, dim3(32), dim3(256), 0, stream,
                       x, mask, xc0, xc1, xc2, jcn);
    hipLaunchKernelGGL(egnn_edges, dim3(2048), dim3(256), 0, stream,
                       x, W1, b1, W2, b2, Wg, bg, gamma, beta,
                       Wn1, bn1, Wn2, bn2, mask, out, xc0, xc1, xc2, jcn);
}